// Round 4
// baseline (222.422 us; speedup 1.0000x reference)
//
#include <hip/hip_runtime.h>
#include <cstdint>
#include <cstddef>

// GRU cell fused: B=16384, I=H=512.
// ws: Wrz bf16 [1024][1024] @0 (2 MB), Wih bf16 [512][1024] @2MB (1 MB).
// X (input|hidden) is reg-staged + converted inside gru_fused (no prep_x).

typedef __attribute__((ext_vector_type(8))) __bf16 bf16x8;
typedef __attribute__((ext_vector_type(4))) float f32x4;
typedef __attribute__((ext_vector_type(8))) unsigned short u16x8;

__device__ __forceinline__ unsigned short f2bf(float f) {
    unsigned u = __builtin_bit_cast(unsigned, f);
    return (unsigned short)((u + 0x7fffu + ((u >> 16) & 1u)) >> 16);  // RNE
}

__global__ void prep_w(const float* __restrict__ Wg, const float* __restrict__ Wi,
                       const float* __restrict__ Wh,
                       unsigned short* __restrict__ Wrz, unsigned short* __restrict__ Wih) {
    int t = blockIdx.x * 256 + threadIdx.x;   // 196608 threads
    if (t < 131072) {                         // W_gate: 1M elements, 8/thread
        const float* src = Wg + (size_t)t * 8;
        u16x8 o;
#pragma unroll
        for (int e = 0; e < 8; ++e) o[e] = f2bf(src[e]);
        *reinterpret_cast<u16x8*>(Wrz + (size_t)t * 8) = o;
    } else {                                  // Wih[n][k] = k<512 ? Wi[n][k] : Wh[n][k-512]
        int u = t - 131072;                   // 512 rows x 128 chunks
        int n = u >> 7;
        int k = (u & 127) << 3;
        const float* src = (k < 512) ? (Wi + (size_t)n * 512 + k)
                                     : (Wh + (size_t)n * 512 + (k - 512));
        u16x8 o;
#pragma unroll
        for (int e = 0; e < 8; ++e) o[e] = f2bf(src[e]);
        *reinterpret_cast<u16x8*>(Wih + (size_t)n * 1024 + k) = o;
    }
}

__device__ __forceinline__ void gload16(const void* g, void* l) {
    __builtin_amdgcn_global_load_lds(
        (const __attribute__((address_space(1))) void*)g,
        (__attribute__((address_space(3))) void*)l, 16, 0, 0);
}

// LDS tiles: rows of 64 bf16 (128 B). 16B-chunk ch of row r stored at chunk (ch ^ (r&7)).
__device__ __forceinline__ bf16x8 ldfrag(const unsigned short* base, int row, int ch) {
    const char* p = (const char*)base + row * 128 + ((ch ^ (row & 7)) << 4);
    return *reinterpret_cast<const bf16x8*>(p);
}

__global__ __launch_bounds__(256, 2) void gru_fused(
        const float* __restrict__ inp,           // [16384][512]
        const float* __restrict__ hid,           // [16384][512]
        const unsigned short* __restrict__ Wr,   // [512][1024] bf16
        const unsigned short* __restrict__ Wz,   // [512][1024] bf16
        const unsigned short* __restrict__ Wih,  // [512][1024] bf16
        const float* __restrict__ bgate,         // [1024]
        const float* __restrict__ bi,            // [512]
        const float* __restrict__ bh,            // [512]
        float* __restrict__ out) {               // [16384][512]
    // BM=128 x BN=64, 4 waves 2x2, wave = 64x32 per gate. BK=64, 16 K-steps.
    __shared__ unsigned short lX[128 * 64];      // 16 KB, single (reg-staged X)
    __shared__ unsigned short lR[2][64 * 64];    // 16 KB dbuf
    __shared__ unsigned short lZ[2][64 * 64];    // 16 KB dbuf
    __shared__ unsigned short lW[2][64 * 64];    // 16 KB dbuf -> 64 KB total

    const int tid = threadIdx.x;
    const int lane = tid & 63;
    const int wid = tid >> 6;
    const int wm = wid >> 1, wn = wid & 1;
    const int bid = blockIdx.x;
    const int bn = bid & 7;                      // spread 8 col-tiles over 8 XCDs
    const int bm = bid >> 3;                     // 128 row tiles

    // --- weight staging bases (global_load_lds, pre-swizzled source) ---
    const int rowa = tid >> 3;                   // 0..31
    const int lc = (tid & 7) ^ (rowa & 7);
    const size_t wbase = ((size_t)(bn * 64 + rowa) * 1024 + lc * 8) * 2;
    const char* gR0 = (const char*)Wr + wbase;  const char* gR1 = gR0 + 65536;
    const char* gZ0 = (const char*)Wz + wbase;  const char* gZ1 = gZ0 + 65536;
    const char* gW0 = (const char*)Wih + wbase; const char* gW1 = gW0 + 65536;

    // --- X reg-staging: thread covers row xr, 32 cols starting at xc ---
    const int xr = tid >> 1;
    const int xc = (tid & 1) * 32;
    const float* xsi = inp + (size_t)(bm * 128 + xr) * 512 + xc;
    const float* xsh = hid + (size_t)(bm * 128 + xr) * 512 + xc;

    float xv[32];

    f32x4 accR[4][2], accZ[4][2], accI[4][2], accH[4][2];
#pragma unroll
    for (int i = 0; i < 4; ++i)
#pragma unroll
        for (int j = 0; j < 2; ++j) {
            accR[i][j] = (f32x4){0.f, 0.f, 0.f, 0.f};
            accZ[i][j] = (f32x4){0.f, 0.f, 0.f, 0.f};
            accI[i][j] = (f32x4){0.f, 0.f, 0.f, 0.f};
            accH[i][j] = (f32x4){0.f, 0.f, 0.f, 0.f};
        }

    const int ra = wm * 64 + (lane & 15);        // A-frag base row
    const int rb = wn * 32 + (lane & 15);        // B-frag base row (out col)
    const int c0 = lane >> 4;                    // k-chunk 0..3

#define XLOAD(t) { const float* s_ = ((t) < 8 ? xsi : xsh) + ((t) & 7) * 64;          \
    _Pragma("unroll") for (int j_ = 0; j_ < 8; ++j_)                                  \
        *reinterpret_cast<f32x4*>(xv + j_ * 4) = reinterpret_cast<const f32x4*>(s_)[j_]; }

#define WLOAD(t, b) {                                                    \
    gload16(gR0 + (t) * 128, (char*)lR[b] + tid * 16);                   \
    gload16(gR1 + (t) * 128, (char*)lR[b] + tid * 16 + 4096);            \
    gload16(gZ0 + (t) * 128, (char*)lZ[b] + tid * 16);                   \
    gload16(gZ1 + (t) * 128, (char*)lZ[b] + tid * 16 + 4096);            \
    gload16(gW0 + (t) * 128, (char*)lW[b] + tid * 16);                   \
    gload16(gW1 + (t) * 128, (char*)lW[b] + tid * 16 + 4096); }

#define XWRITE() {                                                                     \
    _Pragma("unroll") for (int j2 = 0; j2 < 4; ++j2) {                                 \
        u16x8 w_;                                                                      \
        _Pragma("unroll") for (int e_ = 0; e_ < 8; ++e_) w_[e_] = f2bf(xv[j2 * 8 + e_]); \
        *reinterpret_cast<u16x8*>(lX + xr * 64 + ((((xc >> 3) + j2) ^ (xr & 7)) << 3)) = w_; } }

#define MFMA8(ACC, B0, B1)                                                            \
    ACC[0][0] = __builtin_amdgcn_mfma_f32_16x16x32_bf16(a0, B0, ACC[0][0], 0, 0, 0); \
    ACC[1][0] = __builtin_amdgcn_mfma_f32_16x16x32_bf16(a1, B0, ACC[1][0], 0, 0, 0); \
    ACC[2][0] = __builtin_amdgcn_mfma_f32_16x16x32_bf16(a2, B0, ACC[2][0], 0, 0, 0); \
    ACC[3][0] = __builtin_amdgcn_mfma_f32_16x16x32_bf16(a3, B0, ACC[3][0], 0, 0, 0); \
    ACC[0][1] = __builtin_amdgcn_mfma_f32_16x16x32_bf16(a0, B1, ACC[0][1], 0, 0, 0); \
    ACC[1][1] = __builtin_amdgcn_mfma_f32_16x16x32_bf16(a1, B1, ACC[1][1], 0, 0, 0); \
    ACC[2][1] = __builtin_amdgcn_mfma_f32_16x16x32_bf16(a2, B1, ACC[2][1], 0, 0, 0); \
    ACC[3][1] = __builtin_amdgcn_mfma_f32_16x16x32_bf16(a3, B1, ACC[3][1], 0, 0, 0);

#define COMPUTE(b, ACC3)                                                 \
    _Pragma("unroll") for (int ks = 0; ks < 2; ++ks) {                   \
        const int ch = ks * 4 + c0;                                      \
        bf16x8 a0 = ldfrag(lX, ra, ch);                                  \
        bf16x8 a1 = ldfrag(lX, ra + 16, ch);                             \
        bf16x8 a2 = ldfrag(lX, ra + 32, ch);                             \
        bf16x8 a3 = ldfrag(lX, ra + 48, ch);                             \
        bf16x8 b0 = ldfrag(lR[b], rb, ch);                               \
        bf16x8 b1 = ldfrag(lR[b], rb + 16, ch);                          \
        MFMA8(accR, b0, b1)                                              \
        b0 = ldfrag(lZ[b], rb, ch);                                      \
        b1 = ldfrag(lZ[b], rb + 16, ch);                                 \
        MFMA8(accZ, b0, b1)                                              \
        b0 = ldfrag(lW[b], rb, ch);                                      \
        b1 = ldfrag(lW[b], rb + 16, ch);                                 \
        MFMA8(ACC3, b0, b1)                                              \
    }

    // --- prologue: stage tile 0 (latency exposed once) ---
    XLOAD(0)
    WLOAD(0, 0)
    XWRITE()
    asm volatile("s_waitcnt vmcnt(0) lgkmcnt(0)" ::: "memory");
    __builtin_amdgcn_s_barrier();

    // --- pipelined main loop: issue t+1, compute t, write X(t+1) late ---
#pragma unroll
    for (int t = 0; t < 15; ++t) {
        const int nb = (t + 1) & 1;
        XLOAD(t + 1)                              // fp32 X -> regs (compiler-tracked vmcnt)
        WLOAD(t + 1, nb)                          // weights -> LDS dbuf (async DMA)
        if (t < 8) { COMPUTE(t & 1, accI) } else { COMPUTE(t & 1, accH) }
        __builtin_amdgcn_s_barrier();             // all waves done reading lX
        XWRITE()                                  // cvt + ds_write X(t+1)
        asm volatile("s_waitcnt vmcnt(0) lgkmcnt(0)" ::: "memory");  // weights landed + my ds_writes done
        __builtin_amdgcn_s_barrier();             // tile t+1 fully in LDS
    }
    COMPUTE(1, accH)                              // t=15, weights buf 1
#undef COMPUTE
#undef MFMA8
#undef XWRITE
#undef WLOAD
#undef XLOAD

    // --- fused GRU epilogue ---
    const int colb = bn * 64 + wn * 32 + (lane & 15);
    const int rowb = bm * 128 + wm * 64 + ((lane >> 4) << 2);
#pragma unroll
    for (int ni = 0; ni < 2; ++ni) {
        const int n = colb + ni * 16;
        const float bgr = bgate[n];
        const float bgz = bgate[512 + n];
        const float bii = bi[n];
        const float bhh = bh[n];
#pragma unroll
        for (int mi = 0; mi < 4; ++mi) {
#pragma unroll
            for (int r = 0; r < 4; ++r) {
                const int m = rowb + mi * 16 + r;
                const size_t off = (size_t)m * 512 + n;
                float rg = accR[mi][ni][r] + bgr;
                rg = 1.f / (1.f + __expf(-rg));
                float zg = accZ[mi][ni][r] + bgz;
                zg = 1.f / (1.f + __expf(-zg));
                float x = accI[mi][ni][r] + bii + rg * (accH[mi][ni][r] + bhh);
                x = fminf(fmaxf(x, -15.f), 15.f);
                const float e = __expf(2.f * x);
                const float ng = (e - 1.f) / (e + 1.f);   // tanh(x)
                out[off] = ng + zg * (hid[off] - ng);     // (1-z)*n + z*h
            }
        }
    }
}

extern "C" void kernel_launch(void* const* d_in, const int* in_sizes, int n_in,
                              void* d_out, int out_size, void* d_ws, size_t ws_size,
                              hipStream_t stream) {
    const float* inp = (const float*)d_in[0];
    const float* hid = (const float*)d_in[1];
    const float* Wg  = (const float*)d_in[2];
    const float* bg  = (const float*)d_in[3];
    const float* Wi  = (const float*)d_in[4];
    const float* bi  = (const float*)d_in[5];
    const float* Wh  = (const float*)d_in[6];
    const float* bh  = (const float*)d_in[7];
    float* out = (float*)d_out;

    unsigned short* Wrz = (unsigned short*)d_ws;                       // 2 MB
    unsigned short* Wih = (unsigned short*)((char*)d_ws + 2097152);    // 1 MB

    prep_w<<<768, 256, 0, stream>>>(Wg, Wi, Wh, Wrz, Wih);
    gru_fused<<<1024, 256, 0, stream>>>(inp, hid, Wrz, Wrz + 512 * 1024, Wih,
                                        bg, bi, bh, out);
}